// Round 5
// baseline (312.185 us; speedup 1.0000x reference)
//
#include <hip/hip_runtime.h>
#include <math.h>

#define NUM_BINS 20
#define NPAIR    (NUM_BINS / 2)    // bins packed in adjacent pairs (2j, 2j+1)
#define NACC     (3 * NUM_BINS)    // 60 scalar accumulators total
#define BLOCK    256
#define NBLK     1536              // 6 blocks/CU x 4 waves = 24 waves/CU (vs 16 before)

typedef float v2f __attribute__((ext_vector_type(2)));

// w_j(p) = exp(-(p - c_j)^2 / T) = exp2(K1*p*p) * exp2(K2*p)^j * exp2(K1*c_j*c_j)
//   K1 = -1/(T*ln2), K2 = 2/(19*T*ln2), T = 0.1, c_j = j/19
__device__ __host__ constexpr float K1f() { return (float)(-1.0 / (0.1 * 0.6931471805599453)); }
__device__ __host__ constexpr float K2f() { return (float)( 2.0 / (1.9 * 0.6931471805599453)); }

// Minimal-register main loop: float2 elements, no prefetch, no LDS staging.
// Goal: fit <=85 unified VGPR+AGPR regs/thread so 6 waves/SIMD are resident
// (60 accumulator regs + ~18 working regs). __launch_bounds__(256,6) pins it.
__global__ __launch_bounds__(BLOCK, 6) void ace_partial(const float* __restrict__ p,
                                                        const float* __restrict__ t,
                                                        float* __restrict__ partials,
                                                        int n2, int nblk) {
    const float K1 = K1f();
    const float K2 = K2f();

    v2f aW2[NPAIR], aP2[NPAIR], aT2[NPAIR];
#pragma unroll
    for (int jp = 0; jp < NPAIR; ++jp) {
        aW2[jp] = (v2f){0.f, 0.f};
        aP2[jp] = (v2f){0.f, 0.f};
        aT2[jp] = (v2f){0.f, 0.f};
    }

    const float2* __restrict__ p2 = (const float2*)p;
    const float2* __restrict__ t2 = (const float2*)t;

    const int stride = gridDim.x * BLOCK;
    for (int i = blockIdx.x * BLOCK + threadIdx.x; i < n2; i += stride) {
        const float2 pv = p2[i];
        const float2 tv = t2[i];

#pragma unroll
        for (int e = 0; e < 2; ++e) {
            const float pp = (e == 0) ? pv.x : pv.y;
            const float tt = (e == 0) ? tv.x : tv.y;
            float u  = __builtin_amdgcn_exp2f(K1 * pp * pp);  // exp(-p^2/T)
            float G  = __builtin_amdgcn_exp2f(K2 * pp);       // exp(2p/(19T))
            float GG = G * G;
            v2f g2;  g2.x = u;  g2.y = u * G;                 // (u*G^{2jp}, u*G^{2jp+1})
            const v2f GG2 = (v2f){GG, GG};
            const v2f pp2 = (v2f){pp, pp};
            const v2f tt2 = (v2f){tt, tt};
#pragma unroll
            for (int jp = 0; jp < NPAIR; ++jp) {
                aW2[jp] += g2;                                          // v_pk_add_f32
                aP2[jp]  = __builtin_elementwise_fma(g2, pp2, aP2[jp]); // v_pk_fma_f32
                aT2[jp]  = __builtin_elementwise_fma(g2, tt2, aT2[jp]); // v_pk_fma_f32
                g2      *= GG2;                                         // v_pk_mul_f32
            }
        }
    }

    // Wave(64)-level tree reduction of all 60 scalar accumulators
#pragma unroll
    for (int jp = 0; jp < NPAIR; ++jp) {
#pragma unroll
        for (int off = 32; off > 0; off >>= 1) {
            aW2[jp].x += __shfl_down(aW2[jp].x, off, 64);
            aW2[jp].y += __shfl_down(aW2[jp].y, off, 64);
            aP2[jp].x += __shfl_down(aP2[jp].x, off, 64);
            aP2[jp].y += __shfl_down(aP2[jp].y, off, 64);
            aT2[jp].x += __shfl_down(aT2[jp].x, off, 64);
            aT2[jp].y += __shfl_down(aT2[jp].y, off, 64);
        }
    }

    __shared__ float red[BLOCK / 64][NACC];
    const int wave = threadIdx.x >> 6;
    const int lane = threadIdx.x & 63;
    if (lane == 0) {
#pragma unroll
        for (int jp = 0; jp < NPAIR; ++jp) {
            red[wave][2 * jp]                    = aW2[jp].x;
            red[wave][2 * jp + 1]                = aW2[jp].y;
            red[wave][NUM_BINS + 2 * jp]         = aP2[jp].x;
            red[wave][NUM_BINS + 2 * jp + 1]     = aP2[jp].y;
            red[wave][2 * NUM_BINS + 2 * jp]     = aT2[jp].x;
            red[wave][2 * NUM_BINS + 2 * jp + 1] = aT2[jp].y;
        }
    }
    __syncthreads();

    // Transposed layout: partials[acc_idx * nblk + blockIdx.x] -> coalesced final reads
    if (threadIdx.x < NACC) {
        float s = 0.f;
#pragma unroll
        for (int w = 0; w < BLOCK / 64; ++w) s += red[w][threadIdx.x];
        partials[threadIdx.x * nblk + blockIdx.x] = s;
    }
}

__global__ __launch_bounds__(1024) void ace_final(const float* __restrict__ partials,
                                                  float* __restrict__ out,
                                                  int nblk) {
    const float K1 = K1f();

    __shared__ float red[NACC][16];
    __shared__ float sums[NACC];
    int tid = threadIdx.x;

    if (tid < NACC * 16) {
        int j = tid >> 4;
        int k = tid & 15;
        const float4* row4 = (const float4*)(partials + (size_t)j * nblk);
        int n4b = nblk >> 2;
        float s = 0.f;
        for (int b = k; b < n4b; b += 16) {
            float4 v = row4[b];
            s += (v.x + v.y) + (v.z + v.w);
        }
        for (int b = (n4b << 2) + k; b < nblk; b += 16) s += partials[(size_t)j * nblk + b];
        red[j][k] = s;
    }
    __syncthreads();

    if (tid < NACC) {
        float s = 0.f;
#pragma unroll
        for (int k = 0; k < 16; ++k) s += red[tid][k];
        sums[tid] = s;
    }
    __syncthreads();

    if (tid == 0) {
        float acc = 0.f;
        for (int j = 0; j < NUM_BINS; ++j) {
            float c    = (float)j / 19.0f;
            float A    = __builtin_amdgcn_exp2f(K1 * c * c);  // exp(-c^2/T)
            float wsum = A * sums[j];
            float denom = wsum + 1e-8f;
            float e    = (A * sums[NUM_BINS + j]) / denom;
            float o    = (A * sums[2 * NUM_BINS + j]) / denom;
            float contrib = (wsum == 0.0f) ? 0.0f : fabsf(e - o);
            acc += contrib;
        }
        out[0] = acc / (float)NUM_BINS;
    }
}

extern "C" void kernel_launch(void* const* d_in, const int* in_sizes, int n_in,
                              void* d_out, int out_size, void* d_ws, size_t ws_size,
                              hipStream_t stream) {
    const float* preds   = (const float*)d_in[0];
    const float* targets = (const float*)d_in[1];
    float* out           = (float*)d_out;
    float* partials      = (float*)d_ws;

    int n  = in_sizes[0];
    int n2 = n >> 1;   // N = 32*1024*1024, divisible by 2

    int nblk = NBLK;
    size_t need = (size_t)nblk * NACC * sizeof(float);
    if (ws_size < need) {
        nblk = (int)(ws_size / (NACC * sizeof(float)));
        if (nblk < 1) nblk = 1;
    }

    ace_partial<<<nblk, BLOCK, 0, stream>>>(preds, targets, partials, n2, nblk);
    ace_final<<<1, 1024, 0, stream>>>(partials, out, nblk);
}